// Round 2
// baseline (3395.721 us; speedup 1.0000x reference)
//
#include <hip/hip_runtime.h>

// Problem constants
constexpr int S_LEN = 2048;
constexpr int NBATCH = 4;
constexpr int DIN = 4096;
constexpr int DOUT = 1024;

constexpr int BM = 128, BN = 128, BK = 16;

// ---------------------------------------------------------------------------
// fp32 tiled GEMM: C[z] = alpha * A[z] @ (BT ? B[z]^T : B[z]) (+ bias)
// A: [M,K] row-major. B: NN -> [K,N], BT -> [N,K]. C: [M,N].
// 256 threads, 128x128 tile, 8x8 micro-tile split as (4+4)x(4+4).
// ---------------------------------------------------------------------------
template<bool BT, bool BIAS>
__global__ __launch_bounds__(256)
void gemm128(const float* __restrict__ Ab, const float* __restrict__ Bb,
             const float* __restrict__ bias, float* __restrict__ Cb,
             int M, int N, int K,
             long sA, long sB, long sC, float alpha)
{
    const int z = blockIdx.z;
    const float* A = Ab + (long)z * sA;
    const float* B = Bb + (long)z * sB;
    float*       C = Cb + (long)z * sC;

    const int row0 = blockIdx.y * BM;
    const int col0 = blockIdx.x * BN;
    const int tid  = threadIdx.x;
    const int ty4  = (tid >> 4) << 2;   // (tid/16)*4  : 0..60
    const int tx4  = (tid & 15) << 2;   // (tid%16)*4  : 0..60

    __shared__ float As[BK][BM + 4];    // [k][m], +4 pad -> 2-way write conflict (free)
    __shared__ float Bs[BK][BN + 4];

    float acc[8][8];
#pragma unroll
    for (int i = 0; i < 8; ++i)
#pragma unroll
        for (int j = 0; j < 8; ++j) acc[i][j] = 0.f;

    const int ar = tid >> 2;          // 0..63   (row within tile for A / B^T loads)
    const int ak = (tid & 3) << 2;    // 0,4,8,12 (k offset)
    const int br = tid >> 5;          // 0..7    (k row for NN B loads)
    const int bc = (tid & 31) << 2;   // 0..124  (col offset)

    for (int k0 = 0; k0 < K; k0 += BK) {
        float4 a0 = *(const float4*)(A + (long)(row0 + ar)      * K + k0 + ak);
        float4 a1 = *(const float4*)(A + (long)(row0 + ar + 64) * K + k0 + ak);
        float4 b0, b1;
        if (BT) {
            b0 = *(const float4*)(B + (long)(col0 + ar)      * K + k0 + ak);
            b1 = *(const float4*)(B + (long)(col0 + ar + 64) * K + k0 + ak);
        } else {
            b0 = *(const float4*)(B + (long)(k0 + br)     * N + col0 + bc);
            b1 = *(const float4*)(B + (long)(k0 + br + 8) * N + col0 + bc);
        }
        As[ak + 0][ar] = a0.x; As[ak + 1][ar] = a0.y;
        As[ak + 2][ar] = a0.z; As[ak + 3][ar] = a0.w;
        As[ak + 0][ar + 64] = a1.x; As[ak + 1][ar + 64] = a1.y;
        As[ak + 2][ar + 64] = a1.z; As[ak + 3][ar + 64] = a1.w;
        if (BT) {
            Bs[ak + 0][ar] = b0.x; Bs[ak + 1][ar] = b0.y;
            Bs[ak + 2][ar] = b0.z; Bs[ak + 3][ar] = b0.w;
            Bs[ak + 0][ar + 64] = b1.x; Bs[ak + 1][ar + 64] = b1.y;
            Bs[ak + 2][ar + 64] = b1.z; Bs[ak + 3][ar + 64] = b1.w;
        } else {
            *(float4*)&Bs[br][bc]     = b0;
            *(float4*)&Bs[br + 8][bc] = b1;
        }
        __syncthreads();
#pragma unroll
        for (int k = 0; k < BK; ++k) {
            float4 va0 = *(const float4*)&As[k][ty4];
            float4 va1 = *(const float4*)&As[k][ty4 + 64];
            float4 vb0 = *(const float4*)&Bs[k][tx4];
            float4 vb1 = *(const float4*)&Bs[k][tx4 + 64];
            float a[8] = {va0.x, va0.y, va0.z, va0.w, va1.x, va1.y, va1.z, va1.w};
            float b[8] = {vb0.x, vb0.y, vb0.z, vb0.w, vb1.x, vb1.y, vb1.z, vb1.w};
#pragma unroll
            for (int i = 0; i < 8; ++i)
#pragma unroll
                for (int j = 0; j < 8; ++j)
                    acc[i][j] = fmaf(a[i], b[j], acc[i][j]);
        }
        __syncthreads();
    }

    float4 bias0 = make_float4(0.f, 0.f, 0.f, 0.f);
    float4 bias1 = make_float4(0.f, 0.f, 0.f, 0.f);
    if (BIAS) {
        bias0 = *(const float4*)(bias + col0 + tx4);
        bias1 = *(const float4*)(bias + col0 + 64 + tx4);
    }
#pragma unroll
    for (int i = 0; i < 8; ++i) {
        const int r = row0 + ((i < 4) ? (ty4 + i) : (60 + ty4 + i));
        float4 o0, o1;
        o0.x = acc[i][0] * alpha; o0.y = acc[i][1] * alpha;
        o0.z = acc[i][2] * alpha; o0.w = acc[i][3] * alpha;
        o1.x = acc[i][4] * alpha; o1.y = acc[i][5] * alpha;
        o1.z = acc[i][6] * alpha; o1.w = acc[i][7] * alpha;
        if (BIAS) {
            o0.x += bias0.x; o0.y += bias0.y; o0.z += bias0.z; o0.w += bias0.w;
            o1.x += bias1.x; o1.y += bias1.y; o1.z += bias1.z; o1.w += bias1.w;
        }
        *(float4*)(C + (long)r * N + col0 + tx4)      = o0;
        *(float4*)(C + (long)r * N + col0 + 64 + tx4) = o1;
    }
}

// ---------------------------------------------------------------------------
// JAX partitionable-threefry dropout mask (jax_threefry_partitionable=True,
// the default in modern JAX). For a (4,2048,2048) bernoulli(p=0.5) draw with
// key = jax.random.key(42):
//   counts = iota(uint64, 2^24); x_hi = counts>>32 (= 0), x_lo = counts
//   (o0,o1) = threefry2x32(key=(0,42), (x_hi, x_lo))   per element
//   bits = o0 ^ o1                                      (bit_width==32 path)
//   u = bitcast((bits>>9)|0x3f800000) - 1;  keep = u < 0.5  <=>  MSB(bits)==0
// ---------------------------------------------------------------------------
__device__ __forceinline__ unsigned rotl32(unsigned x, int r) {
    return (x << r) | (x >> (32 - r));
}

__device__ __forceinline__ bool tf_keep(unsigned i) {
    const unsigned k0 = 0u, k1 = 42u, k2 = 0x1BD11BF0u; // 0x1BD11BDA ^ 0 ^ 42
    unsigned x0 = 0u;        // x_hi + k0 = 0
    unsigned x1 = i + k1;    // x_lo + k1
#define TF_R4(r0, r1, r2, r3) \
    x0 += x1; x1 = rotl32(x1, r0); x1 ^= x0; \
    x0 += x1; x1 = rotl32(x1, r1); x1 ^= x0; \
    x0 += x1; x1 = rotl32(x1, r2); x1 ^= x0; \
    x0 += x1; x1 = rotl32(x1, r3); x1 ^= x0;
    TF_R4(13, 15, 26, 6)  x0 += k1; x1 += k2 + 1u;
    TF_R4(17, 29, 16, 24) x0 += k2; x1 += k0 + 2u;
    TF_R4(13, 15, 26, 6)  x0 += k0; x1 += k1 + 3u;
    TF_R4(17, 29, 16, 24) x0 += k1; x1 += k2 + 4u;
    TF_R4(13, 15, 26, 6)  x0 += k2; x1 += k0 + 5u;
#undef TF_R4
    const unsigned bits = x0 ^ x1;
    return (bits >> 31) == 0u;   // uniform(bits) < 0.5
}

// ---------------------------------------------------------------------------
// Fused row softmax + dropout (p=0.5, scale 2x) over scores [B*S, S].
// One 256-thread block per row of 2048.
// ---------------------------------------------------------------------------
__global__ __launch_bounds__(256)
void softmax_dropout(float* __restrict__ sc)
{
    const int r = blockIdx.x;                 // 0..B*S-1
    float* row = sc + (long)r * S_LEN;
    const int tid = threadIdx.x;

    float4 v0 = *(float4*)(row + tid * 4);
    float4 v1 = *(float4*)(row + 1024 + tid * 4);

    float m = fmaxf(fmaxf(fmaxf(v0.x, v0.y), fmaxf(v0.z, v0.w)),
                    fmaxf(fmaxf(v1.x, v1.y), fmaxf(v1.z, v1.w)));
#pragma unroll
    for (int off = 32; off > 0; off >>= 1) m = fmaxf(m, __shfl_xor(m, off));

    __shared__ float red[8];
    if ((tid & 63) == 0) red[tid >> 6] = m;
    __syncthreads();
    m = fmaxf(fmaxf(red[0], red[1]), fmaxf(red[2], red[3]));

    v0.x = __expf(v0.x - m); v0.y = __expf(v0.y - m);
    v0.z = __expf(v0.z - m); v0.w = __expf(v0.w - m);
    v1.x = __expf(v1.x - m); v1.y = __expf(v1.y - m);
    v1.z = __expf(v1.z - m); v1.w = __expf(v1.w - m);

    float s = v0.x + v0.y + v0.z + v0.w + v1.x + v1.y + v1.z + v1.w;
#pragma unroll
    for (int off = 32; off > 0; off >>= 1) s += __shfl_xor(s, off);
    if ((tid & 63) == 0) red[4 + (tid >> 6)] = s;
    __syncthreads();
    s = red[4] + red[5] + red[6] + red[7];

    const float inv = 2.0f / s;               // 1/(1-p) * 1/sum

    const unsigned base0 = (unsigned)r * 2048u + (unsigned)(tid * 4);
    const unsigned base1 = base0 + 1024u;
    v0.x = tf_keep(base0 + 0u) ? v0.x * inv : 0.f;
    v0.y = tf_keep(base0 + 1u) ? v0.y * inv : 0.f;
    v0.z = tf_keep(base0 + 2u) ? v0.z * inv : 0.f;
    v0.w = tf_keep(base0 + 3u) ? v0.w * inv : 0.f;
    v1.x = tf_keep(base1 + 0u) ? v1.x * inv : 0.f;
    v1.y = tf_keep(base1 + 1u) ? v1.y * inv : 0.f;
    v1.z = tf_keep(base1 + 2u) ? v1.z * inv : 0.f;
    v1.w = tf_keep(base1 + 3u) ? v1.w * inv : 0.f;

    *(float4*)(row + tid * 4)        = v0;
    *(float4*)(row + 1024 + tid * 4) = v1;
}

// ---------------------------------------------------------------------------
extern "C" void kernel_launch(void* const* d_in, const int* in_sizes, int n_in,
                              void* d_out, int out_size, void* d_ws, size_t ws_size,
                              hipStream_t stream)
{
    const float* x1 = (const float*)d_in[0];
    const float* Wq = (const float*)d_in[1];
    const float* bq = (const float*)d_in[2];
    const float* Wk = (const float*)d_in[3];
    const float* bk = (const float*)d_in[4];
    const float* Wv = (const float*)d_in[5];
    const float* bv = (const float*)d_in[6];
    float* out = (float*)d_out;
    float* ws  = (float*)d_ws;

    const long QKV = (long)NBATCH * S_LEN * DOUT;      // 8,388,608
    float* q  = ws;
    float* k  = ws + QKV;
    float* v  = ws + 2 * QKV;
    float* sc = ws + 3 * QKV;                          // 16,777,216 floats

    const int M = NBATCH * S_LEN;                      // 8192
    dim3 blk(256);

    // QKV projections: [8192,4096] @ [4096,1024] + bias
    gemm128<false, true><<<dim3(DOUT / BN, M / BM, 1), blk, 0, stream>>>(
        x1, Wq, bq, q, M, DOUT, DIN, 0, 0, 0, 1.0f);
    gemm128<false, true><<<dim3(DOUT / BN, M / BM, 1), blk, 0, stream>>>(
        x1, Wk, bk, k, M, DOUT, DIN, 0, 0, 0, 1.0f);
    gemm128<false, true><<<dim3(DOUT / BN, M / BM, 1), blk, 0, stream>>>(
        x1, Wv, bv, v, M, DOUT, DIN, 0, 0, 0, 1.0f);

    // scores = q @ k^T / 32 per batch: [2048,1024] x [2048,1024]^T
    gemm128<true, false><<<dim3(S_LEN / BN, S_LEN / BM, NBATCH), blk, 0, stream>>>(
        q, k, nullptr, sc, S_LEN, S_LEN, DOUT,
        (long)S_LEN * DOUT, (long)S_LEN * DOUT, (long)S_LEN * S_LEN, 1.0f / 32.0f);

    // softmax + exact-JAX (partitionable threefry) dropout, in place
    softmax_dropout<<<dim3(NBATCH * S_LEN), blk, 0, stream>>>(sc);

    // out = attn @ v per batch: [2048,2048] x [2048,1024]
    gemm128<false, false><<<dim3(DOUT / BN, S_LEN / BM, NBATCH), blk, 0, stream>>>(
        sc, v, nullptr, out, S_LEN, DOUT, S_LEN,
        (long)S_LEN * S_LEN, (long)S_LEN * DOUT, (long)S_LEN * DOUT, 1.0f);
}

// Round 3
// 1300.948 us; speedup vs baseline: 2.6102x; 2.6102x over previous
//
#include <hip/hip_runtime.h>

typedef __attribute__((ext_vector_type(8))) short  short8;
typedef __attribute__((ext_vector_type(4))) float  floatx4;
typedef __attribute__((ext_vector_type(4))) unsigned short ushort4v;

constexpr int S_LEN = 2048;
constexpr int NB    = 4;
constexpr int DIN   = 4096;
constexpr int DOUT  = 1024;

// ---------------------------------------------------------------------------
// bf16 helpers: RNE high part, truncated low residual (hi+lo ~ fp32 to 2^-17)
// ---------------------------------------------------------------------------
__device__ __forceinline__ unsigned short bf16_rne(float x) {
    unsigned u = __builtin_bit_cast(unsigned, x);
    u += 0x7fffu + ((u >> 16) & 1u);
    return (unsigned short)(u >> 16);
}
__device__ __forceinline__ void split8(const float* f, short8& h8, short8& l8) {
#pragma unroll
    for (int j = 0; j < 8; ++j) {
        unsigned u  = __builtin_bit_cast(unsigned, f[j]);
        unsigned ur = u + 0x7fffu + ((u >> 16) & 1u);
        float hif   = __builtin_bit_cast(float, ur & 0xffff0000u);
        float lo    = f[j] - hif;
        h8[j] = (short)(ur >> 16);
        l8[j] = (short)(__builtin_bit_cast(unsigned, lo) >> 16);
    }
}
__device__ __forceinline__ void plain8(const float* f, short8& h8) {
#pragma unroll
    for (int j = 0; j < 8; ++j) {
        unsigned u  = __builtin_bit_cast(unsigned, f[j]);
        unsigned ur = u + 0x7fffu + ((u >> 16) & 1u);
        h8[j] = (short)(ur >> 16);
    }
}

// ---------------------------------------------------------------------------
// Templated MFMA GEMM: C = alpha * A @ B^T (+ bias), tile 128x128, BK=32.
// A: AKIND==0 -> f32 [M,K] (converted/split on the fly), AKIND==1 -> bf16
// planes Ah(,Al) [M,K]. B: always bf16 planes Bh(,Bl) [N,K].
// APL/BPL = planes used (split => hh + h*l + l*h products).
// CMODE: 0 = f32 [M,N]; 1 = bf16 pair [M,N]; 2 = bf16 transposed (vT layout
//        [z][DOUT][S_LEN], z = global_row>>11).
// ---------------------------------------------------------------------------
template<int AKIND, int APL, int BPL, int CMODE, bool BIAS>
__global__ __launch_bounds__(256, 2)
void mfma_gemm(const void* Av, const unsigned short* __restrict__ Al_,
               const unsigned short* __restrict__ Bh_, const unsigned short* __restrict__ Bl_,
               const float* __restrict__ bias, float alpha,
               float* __restrict__ Cf, unsigned short* __restrict__ Ch,
               unsigned short* __restrict__ Cl,
               int M, int N, int K, int lda, int ldb, int ldc,
               long sAz, long sBz, long sCz)
{
    const int z   = blockIdx.z;
    const int m0  = blockIdx.y * 128;
    const int n0  = blockIdx.x * 128;
    const int tid = threadIdx.x;
    const int lane = tid & 63;
    const int wid  = tid >> 6;
    const int wm   = (wid >> 1) * 64;   // wave row offset in tile
    const int wn   = (wid & 1) * 64;    // wave col offset
    const int l15  = lane & 15;
    const int l4   = lane >> 4;         // 0..3

    // LDS planes [128][32] bf16, 16B-unit swizzle: unit ^= (row>>1)&3
    __shared__ unsigned short Ash[128 * 32];
    __shared__ unsigned short Bsh[128 * 32];
    __shared__ unsigned short Asl[(APL == 2) ? 128 * 32 : 8];
    __shared__ unsigned short Bsl[(BPL == 2) ? 128 * 32 : 8];

    floatx4 acc[4][4];
#pragma unroll
    for (int i = 0; i < 4; ++i)
#pragma unroll
        for (int j = 0; j < 4; ++j) acc[i][j] = (floatx4)0.f;

    const int sr = tid & 127;       // staging row
    const int sh = tid >> 7;        // staging half (16 elems)
    const int sw = (sr >> 1) & 3;   // swizzle for this row
    const int wofs0 = sr * 32 + (((sh * 2 + 0) ^ sw) << 3);
    const int wofs1 = sr * 32 + (((sh * 2 + 1) ^ sw) << 3);

    for (int k0 = 0; k0 < K; k0 += 32) {
        short8 wAh[2], wAl[2], wBh[2], wBl[2];
        if constexpr (AKIND == 0) {
            const float* Ap = (const float*)Av + (long)z * sAz + (long)(m0 + sr) * lda + k0 + sh * 16;
            float f[16];
            *(float4*)&f[0]  = *(const float4*)(Ap + 0);
            *(float4*)&f[4]  = *(const float4*)(Ap + 4);
            *(float4*)&f[8]  = *(const float4*)(Ap + 8);
            *(float4*)&f[12] = *(const float4*)(Ap + 12);
            if constexpr (APL == 2) { split8(f, wAh[0], wAl[0]); split8(f + 8, wAh[1], wAl[1]); }
            else                    { plain8(f, wAh[0]);        plain8(f + 8, wAh[1]); }
        } else {
            const unsigned short* Ap = (const unsigned short*)Av + (long)z * sAz + (long)(m0 + sr) * lda + k0 + sh * 16;
            wAh[0] = *(const short8*)(Ap + 0);
            wAh[1] = *(const short8*)(Ap + 8);
            if constexpr (APL == 2) {
                const unsigned short* Ap2 = Al_ + (long)z * sAz + (long)(m0 + sr) * lda + k0 + sh * 16;
                wAl[0] = *(const short8*)(Ap2 + 0);
                wAl[1] = *(const short8*)(Ap2 + 8);
            }
        }
        {
            const unsigned short* Bp = Bh_ + (long)z * sBz + (long)(n0 + sr) * ldb + k0 + sh * 16;
            wBh[0] = *(const short8*)(Bp + 0);
            wBh[1] = *(const short8*)(Bp + 8);
            if constexpr (BPL == 2) {
                const unsigned short* Bp2 = Bl_ + (long)z * sBz + (long)(n0 + sr) * ldb + k0 + sh * 16;
                wBl[0] = *(const short8*)(Bp2 + 0);
                wBl[1] = *(const short8*)(Bp2 + 8);
            }
        }

        __syncthreads();   // previous iteration's fragment reads complete
        *(short8*)&Ash[wofs0] = wAh[0];
        *(short8*)&Ash[wofs1] = wAh[1];
        *(short8*)&Bsh[wofs0] = wBh[0];
        *(short8*)&Bsh[wofs1] = wBh[1];
        if constexpr (APL == 2) { *(short8*)&Asl[wofs0] = wAl[0]; *(short8*)&Asl[wofs1] = wAl[1]; }
        if constexpr (BPL == 2) { *(short8*)&Bsl[wofs0] = wBl[0]; *(short8*)&Bsl[wofs1] = wBl[1]; }
        __syncthreads();   // tile ready

        short8 a_h[4], a_l[4], b_h[4], b_l[4];
#pragma unroll
        for (int i = 0; i < 4; ++i) {
            const int ra = wm + i * 16 + l15;
            const int ca = ra * 32 + ((l4 ^ ((ra >> 1) & 3)) << 3);
            a_h[i] = *(const short8*)&Ash[ca];
            if constexpr (APL == 2) a_l[i] = *(const short8*)&Asl[ca];
            const int rb = wn + i * 16 + l15;
            const int cb = rb * 32 + ((l4 ^ ((rb >> 1) & 3)) << 3);
            b_h[i] = *(const short8*)&Bsh[cb];
            if constexpr (BPL == 2) b_l[i] = *(const short8*)&Bsl[cb];
        }
#pragma unroll
        for (int i = 0; i < 4; ++i)
#pragma unroll
            for (int j = 0; j < 4; ++j) {
                acc[i][j] = __builtin_amdgcn_mfma_f32_16x16x32_bf16(a_h[i], b_h[j], acc[i][j], 0, 0, 0);
                if constexpr (BPL == 2)
                    acc[i][j] = __builtin_amdgcn_mfma_f32_16x16x32_bf16(a_h[i], b_l[j], acc[i][j], 0, 0, 0);
                if constexpr (APL == 2)
                    acc[i][j] = __builtin_amdgcn_mfma_f32_16x16x32_bf16(a_l[i], b_h[j], acc[i][j], 0, 0, 0);
            }
    }

    // ---- epilogue ----
#pragma unroll
    for (int j = 0; j < 4; ++j) {
        const int col = n0 + wn + j * 16 + l15;
        const float bv = BIAS ? bias[col] : 0.f;
#pragma unroll
        for (int i = 0; i < 4; ++i) {
            const int rbase = m0 + wm + i * 16 + l4 * 4;
            float vals[4];
            vals[0] = acc[i][j].x * alpha + bv;
            vals[1] = acc[i][j].y * alpha + bv;
            vals[2] = acc[i][j].z * alpha + bv;
            vals[3] = acc[i][j].w * alpha + bv;
            if constexpr (CMODE == 0) {
#pragma unroll
                for (int r = 0; r < 4; ++r)
                    Cf[(long)z * sCz + (long)(rbase + r) * ldc + col] = vals[r];
            } else if constexpr (CMODE == 1) {
#pragma unroll
                for (int r = 0; r < 4; ++r) {
                    const long idx = (long)(rbase + r) * ldc + col;
                    unsigned u  = __builtin_bit_cast(unsigned, vals[r]);
                    unsigned ur = u + 0x7fffu + ((u >> 16) & 1u);
                    float hif   = __builtin_bit_cast(float, ur & 0xffff0000u);
                    Ch[idx] = (unsigned short)(ur >> 16);
                    Cl[idx] = (unsigned short)(__builtin_bit_cast(unsigned, vals[r] - hif) >> 16);
                }
            } else {  // CMODE == 2: vT[z2][col][s], z2 = rbase>>11, s = rbase&2047
                const int z2 = rbase >> 11;
                const int s0 = rbase & 2047;
                ushort4v p;
                p[0] = bf16_rne(vals[0]); p[1] = bf16_rne(vals[1]);
                p[2] = bf16_rne(vals[2]); p[3] = bf16_rne(vals[3]);
                *(ushort4v*)&Ch[(long)z2 * DOUT * S_LEN + (long)col * S_LEN + s0] = p;
            }
        }
    }
}

// ---------------------------------------------------------------------------
// Weight transpose + split: W [4096,1024] f32 -> Wt_hi/Wt_lo [1024,4096] bf16
// grid (16 n-tiles, 64 k-tiles, 3 weights)
// ---------------------------------------------------------------------------
__global__ __launch_bounds__(256)
void wsplitT(const float* __restrict__ W0, const float* __restrict__ W1,
             const float* __restrict__ W2, unsigned short* __restrict__ base)
{
    const long SZW = (long)DOUT * DIN;  // 4,194,304
    const int z = blockIdx.z;
    const float* W = (z == 0) ? W0 : (z == 1) ? W1 : W2;
    unsigned short* Dh = base + (long)z * 2 * SZW;
    unsigned short* Dl = Dh + SZW;

    __shared__ float t[64][65];
    const int k0 = blockIdx.y * 64, n0 = blockIdx.x * 64;
    const int tid = threadIdx.x;
#pragma unroll
    for (int i = 0; i < 4; ++i) {
        const int kk = (tid >> 4) + i * 16;
        const int nn = (tid & 15) * 4;
        float4 f = *(const float4*)(W + (long)(k0 + kk) * DOUT + n0 + nn);
        t[kk][nn + 0] = f.x; t[kk][nn + 1] = f.y;
        t[kk][nn + 2] = f.z; t[kk][nn + 3] = f.w;
    }
    __syncthreads();
    const int n = tid >> 2, kc = (tid & 3) * 16;
    float xs[16];
#pragma unroll
    for (int jj = 0; jj < 16; ++jj) xs[jj] = t[kc + jj][n];
    short8 h0, h1, l0, l1;
    split8(xs, h0, l0); split8(xs + 8, h1, l1);
    const long o = (long)(n0 + n) * DIN + k0 + kc;
    *(short8*)&Dh[o] = h0; *(short8*)&Dh[o + 8] = h1;
    *(short8*)&Dl[o] = l0; *(short8*)&Dl[o + 8] = l1;
}

// ---------------------------------------------------------------------------
// Threefry-2x32 (jax_threefry_partitionable=True), key=(0,42):
// per element i: (o0,o1)=threefry((0,42),(0,i)); keep = MSB(o0^o1)==0
// ---------------------------------------------------------------------------
__device__ __forceinline__ unsigned rotl32(unsigned x, int r) {
    return (x << r) | (x >> (32 - r));
}
__device__ __forceinline__ bool tf_keep(unsigned i) {
    const unsigned k0 = 0u, k1 = 42u, k2 = 0x1BD11BF0u;
    unsigned x0 = 0u;
    unsigned x1 = i + k1;
#define TF_R4(r0, r1, r2, r3) \
    x0 += x1; x1 = rotl32(x1, r0); x1 ^= x0; \
    x0 += x1; x1 = rotl32(x1, r1); x1 ^= x0; \
    x0 += x1; x1 = rotl32(x1, r2); x1 ^= x0; \
    x0 += x1; x1 = rotl32(x1, r3); x1 ^= x0;
    TF_R4(13, 15, 26, 6)  x0 += k1; x1 += k2 + 1u;
    TF_R4(17, 29, 16, 24) x0 += k2; x1 += k0 + 2u;
    TF_R4(13, 15, 26, 6)  x0 += k0; x1 += k1 + 3u;
    TF_R4(17, 29, 16, 24) x0 += k1; x1 += k2 + 4u;
    TF_R4(13, 15, 26, 6)  x0 += k2; x1 += k0 + 5u;
#undef TF_R4
    return ((x0 ^ x1) >> 31) == 0u;
}

// ---------------------------------------------------------------------------
// Row softmax + dropout: scores f32 [8192][2048] -> attn bf16 [8192][2048]
// ---------------------------------------------------------------------------
__global__ __launch_bounds__(256)
void softmax_dropout(const float* __restrict__ sc, unsigned short* __restrict__ attn)
{
    const int r = blockIdx.x;
    const float* row = sc + (long)r * S_LEN;
    const int tid = threadIdx.x;

    float4 v0 = *(const float4*)(row + tid * 4);
    float4 v1 = *(const float4*)(row + 1024 + tid * 4);

    float m = fmaxf(fmaxf(fmaxf(v0.x, v0.y), fmaxf(v0.z, v0.w)),
                    fmaxf(fmaxf(v1.x, v1.y), fmaxf(v1.z, v1.w)));
#pragma unroll
    for (int off = 32; off > 0; off >>= 1) m = fmaxf(m, __shfl_xor(m, off));

    __shared__ float red[8];
    if ((tid & 63) == 0) red[tid >> 6] = m;
    __syncthreads();
    m = fmaxf(fmaxf(red[0], red[1]), fmaxf(red[2], red[3]));

    v0.x = __expf(v0.x - m); v0.y = __expf(v0.y - m);
    v0.z = __expf(v0.z - m); v0.w = __expf(v0.w - m);
    v1.x = __expf(v1.x - m); v1.y = __expf(v1.y - m);
    v1.z = __expf(v1.z - m); v1.w = __expf(v1.w - m);

    float s = v0.x + v0.y + v0.z + v0.w + v1.x + v1.y + v1.z + v1.w;
#pragma unroll
    for (int off = 32; off > 0; off >>= 1) s += __shfl_xor(s, off);
    if ((tid & 63) == 0) red[4 + (tid >> 6)] = s;
    __syncthreads();
    s = red[4] + red[5] + red[6] + red[7];

    const float inv = 2.0f / s;

    const unsigned base0 = (unsigned)r * 2048u + (unsigned)(tid * 4);
    const unsigned base1 = base0 + 1024u;
    float o[8];
    o[0] = tf_keep(base0 + 0u) ? v0.x * inv : 0.f;
    o[1] = tf_keep(base0 + 1u) ? v0.y * inv : 0.f;
    o[2] = tf_keep(base0 + 2u) ? v0.z * inv : 0.f;
    o[3] = tf_keep(base0 + 3u) ? v0.w * inv : 0.f;
    o[4] = tf_keep(base1 + 0u) ? v1.x * inv : 0.f;
    o[5] = tf_keep(base1 + 1u) ? v1.y * inv : 0.f;
    o[6] = tf_keep(base1 + 2u) ? v1.z * inv : 0.f;
    o[7] = tf_keep(base1 + 3u) ? v1.w * inv : 0.f;

    ushort4v p0, p1;
    p0[0] = bf16_rne(o[0]); p0[1] = bf16_rne(o[1]);
    p0[2] = bf16_rne(o[2]); p0[3] = bf16_rne(o[3]);
    p1[0] = bf16_rne(o[4]); p1[1] = bf16_rne(o[5]);
    p1[2] = bf16_rne(o[6]); p1[3] = bf16_rne(o[7]);
    *(ushort4v*)(attn + (long)r * S_LEN + tid * 4)        = p0;
    *(ushort4v*)(attn + (long)r * S_LEN + 1024 + tid * 4) = p1;
}

// ---------------------------------------------------------------------------
extern "C" void kernel_launch(void* const* d_in, const int* in_sizes, int n_in,
                              void* d_out, int out_size, void* d_ws, size_t ws_size,
                              hipStream_t stream)
{
    const float* x1 = (const float*)d_in[0];
    const float* Wq = (const float*)d_in[1];
    const float* bq = (const float*)d_in[2];
    const float* Wk = (const float*)d_in[3];
    const float* bk = (const float*)d_in[4];
    const float* Wv = (const float*)d_in[5];
    const float* bv = (const float*)d_in[6];
    float* out = (float*)d_out;

    const int M = NB * S_LEN;                       // 8192
    const long SZW  = (long)DOUT * DIN;             // 4,194,304 (bf16 plane)
    const long SZQK = (long)M * DOUT;               // 8,388,608 (bf16 plane)

    // ws layout (151.1 MB total):
    //  [0, 67.1MB)  scores f32 (16,777,216 f32); W-planes (50.3MB) alias this
    //               region and are dead before QK^T writes scores.
    //  [67.1, 100.7) q_hi/q_lo;  attn bf16 aliases this after QK^T.
    //  [100.7,134.2) k_hi/k_lo
    //  [134.2,151.1) vT bf16
    float*          scores = (float*)d_ws;
    unsigned short* Wbase  = (unsigned short*)d_ws;
    unsigned short* qh = (unsigned short*)d_ws + ((long)16777216 * 2);  // 67.1MB in ushorts
    unsigned short* ql = qh + SZQK;
    unsigned short* kh = ql + SZQK;
    unsigned short* kl = kh + SZQK;
    unsigned short* vT = kl + SZQK;
    unsigned short* attn = qh;

    unsigned short* Wq_h = Wbase;
    unsigned short* Wq_l = Wq_h + SZW;
    unsigned short* Wk_h = Wq_l + SZW;
    unsigned short* Wk_l = Wk_h + SZW;
    unsigned short* Wv_h = Wk_l + SZW;

    dim3 blk(256);

    // 1) transpose+split weights into W region
    wsplitT<<<dim3(DOUT / 64, DIN / 64, 3), blk, 0, stream>>>(Wq, Wk, Wv, Wbase);

    // 2) q = x1 @ Wq + bq  (split x split -> near-fp32), write bf16 pair
    mfma_gemm<0, 2, 2, 1, true><<<dim3(DOUT / 128, M / 128, 1), blk, 0, stream>>>(
        x1, nullptr, Wq_h, Wq_l, bq, 1.f, nullptr, qh, ql,
        M, DOUT, DIN, DIN, DIN, DOUT, 0, 0, 0);
    // 3) k likewise
    mfma_gemm<0, 2, 2, 1, true><<<dim3(DOUT / 128, M / 128, 1), blk, 0, stream>>>(
        x1, nullptr, Wk_h, Wk_l, bk, 1.f, nullptr, kh, kl,
        M, DOUT, DIN, DIN, DIN, DOUT, 0, 0, 0);
    // 4) v = x1 @ Wv + bv (plain bf16), write transposed vT[z][d][s]
    mfma_gemm<0, 1, 1, 2, true><<<dim3(DOUT / 128, M / 128, 1), blk, 0, stream>>>(
        x1, nullptr, Wv_h, nullptr, bv, 1.f, nullptr, vT, nullptr,
        M, DOUT, DIN, DIN, DIN, DOUT, 0, 0, 0);

    // 5) scores = q @ k^T / 32 per batch (split x split)
    mfma_gemm<1, 2, 2, 0, false><<<dim3(S_LEN / 128, S_LEN / 128, NB), blk, 0, stream>>>(
        qh, ql, kh, kl, nullptr, 1.f / 32.f, scores, nullptr, nullptr,
        S_LEN, S_LEN, DOUT, DOUT, DOUT, S_LEN,
        (long)S_LEN * DOUT, (long)S_LEN * DOUT, (long)S_LEN * S_LEN);

    // 6) softmax + exact-JAX dropout -> attn bf16 (over q region)
    softmax_dropout<<<dim3(M), blk, 0, stream>>>(scores, attn);

    // 7) out = attn @ vT^T per batch (plain bf16)
    mfma_gemm<1, 1, 1, 0, false><<<dim3(DOUT / 128, S_LEN / 128, NB), blk, 0, stream>>>(
        attn, nullptr, vT, nullptr, nullptr, 1.f, out, nullptr, nullptr,
        S_LEN, DOUT, S_LEN, S_LEN, S_LEN, DOUT,
        (long)S_LEN * S_LEN, (long)DOUT * S_LEN, (long)S_LEN * DOUT);
}

// Round 4
// 847.285 us; speedup vs baseline: 4.0078x; 1.5354x over previous
//
#include <hip/hip_runtime.h>

typedef __attribute__((ext_vector_type(8))) short  short8;
typedef __attribute__((ext_vector_type(4))) float  floatx4;
typedef __attribute__((ext_vector_type(4))) unsigned short ushort4v;
typedef unsigned short ushort;

constexpr int S_LEN = 2048;
constexpr int NB    = 4;
constexpr int DIN   = 4096;
constexpr int DOUT  = 1024;

// ---------------------------------------------------------------------------
// bf16 helpers
// ---------------------------------------------------------------------------
__device__ __forceinline__ ushort bf16_rne(float x) {
    unsigned u = __builtin_bit_cast(unsigned, x);
    u += 0x7fffu + ((u >> 16) & 1u);
    return (ushort)(u >> 16);
}
__device__ __forceinline__ void split8(const float* f, short8& h8, short8& l8) {
#pragma unroll
    for (int j = 0; j < 8; ++j) {
        unsigned u  = __builtin_bit_cast(unsigned, f[j]);
        unsigned ur = u + 0x7fffu + ((u >> 16) & 1u);
        float hif   = __builtin_bit_cast(float, ur & 0xffff0000u);
        float lo    = f[j] - hif;
        h8[j] = (short)(ur >> 16);
        l8[j] = (short)(__builtin_bit_cast(unsigned, lo) >> 16);
    }
}
__device__ __forceinline__ void plain8(const float* f, short8& h8) {
#pragma unroll
    for (int j = 0; j < 8; ++j) {
        unsigned u  = __builtin_bit_cast(unsigned, f[j]);
        unsigned ur = u + 0x7fffu + ((u >> 16) & 1u);
        h8[j] = (short)(ur >> 16);
    }
}

// ---------------------------------------------------------------------------
// Pipelined bf16 MFMA GEMM: C = alpha * A @ B^T (+ bias), 128x128 tile, BK=32.
// A planes (Ah_, Al_) [M,K]; B planes (Bh_, Bl_) [N,K], all bf16 row-major.
// NPROD: 1 = ah*bh; 2 = ah*(bh+bl); 3 = ah*bh + ah*bl + al*bh.
// CMODE: 0 = f32 [M,N] (per z); 1 = bf16 hi/lo pairs, col<1024 -> (Ch0,Cl0)
//        else (Ch1,Cl1) at col-1024, ldc=1024; 2 = bf16 transposed vT layout
//        [row>>11][col][row&2047].
// BIASMODE: 0 none; 1 bias0[col]; 2 col<1024 ? bias0[col] : bias1[col-1024].
// ---------------------------------------------------------------------------
template<int APL, int BPL, int NPROD, int CMODE, int BIASMODE>
__global__ __launch_bounds__(256, 2)
void mfma_gemm(const ushort* __restrict__ Ah_, const ushort* __restrict__ Al_,
               const ushort* __restrict__ Bh_, const ushort* __restrict__ Bl_,
               const float* __restrict__ bias0, const float* __restrict__ bias1,
               float alpha, float* __restrict__ Cf,
               ushort* __restrict__ Ch0, ushort* __restrict__ Cl0,
               ushort* __restrict__ Ch1, ushort* __restrict__ Cl1,
               int M, int N, int K, int lda, int ldb, int ldc,
               long sAz, long sBz, long sCz)
{
    const int z    = blockIdx.z;
    const int m0   = blockIdx.y * 128;
    const int n0   = blockIdx.x * 128;
    const int tid  = threadIdx.x;
    const int lane = tid & 63;
    const int wid  = tid >> 6;
    const int wm   = (wid >> 1) * 64;
    const int wn   = (wid & 1) * 64;
    const int l15  = lane & 15;
    const int l4   = lane >> 4;

    __shared__ ushort Ash[128 * 32];
    __shared__ ushort Bsh[128 * 32];
    __shared__ ushort Asl[(APL == 2) ? 128 * 32 : 8];
    __shared__ ushort Bsl[(BPL == 2) ? 128 * 32 : 8];

    floatx4 acc[4][4];
#pragma unroll
    for (int i = 0; i < 4; ++i)
#pragma unroll
        for (int j = 0; j < 4; ++j) acc[i][j] = (floatx4)0.f;

    // staging: thread t -> row sr = t>>1 (0..127), k-half sh = t&1 (16 elems)
    const int sr = tid >> 1;
    const int sh = tid & 1;
    const int sw = (sr >> 1) & 3;                     // 16B-unit swizzle
    const int wofs0 = sr * 32 + (((sh * 2 + 0) ^ sw) << 3);
    const int wofs1 = sr * 32 + (((sh * 2 + 1) ^ sw) << 3);
    const long zA = (long)z * sAz;
    const long zB = (long)z * sBz;
    const long aoff = zA + (long)(m0 + sr) * lda + sh * 16;
    const long boff = zB + (long)(n0 + sr) * ldb + sh * 16;

    short8 rAh[2], rAl[2], rBh[2], rBl[2];
#define LOADREGS(K0)                                                          \
    do {                                                                      \
        const ushort* Ap = Ah_ + aoff + (K0);                                 \
        rAh[0] = *(const short8*)(Ap);                                        \
        rAh[1] = *(const short8*)(Ap + 8);                                    \
        if constexpr (APL == 2) {                                             \
            const ushort* Ap2 = Al_ + aoff + (K0);                            \
            rAl[0] = *(const short8*)(Ap2);                                   \
            rAl[1] = *(const short8*)(Ap2 + 8);                               \
        }                                                                     \
        const ushort* Bp = Bh_ + boff + (K0);                                 \
        rBh[0] = *(const short8*)(Bp);                                        \
        rBh[1] = *(const short8*)(Bp + 8);                                    \
        if constexpr (BPL == 2) {                                             \
            const ushort* Bp2 = Bl_ + boff + (K0);                            \
            rBl[0] = *(const short8*)(Bp2);                                   \
            rBl[1] = *(const short8*)(Bp2 + 8);                               \
        }                                                                     \
    } while (0)

    LOADREGS(0);

    for (int k0 = 0; k0 < K; k0 += 32) {
        __syncthreads();   // previous tile's fragment reads complete
        *(short8*)&Ash[wofs0] = rAh[0];
        *(short8*)&Ash[wofs1] = rAh[1];
        *(short8*)&Bsh[wofs0] = rBh[0];
        *(short8*)&Bsh[wofs1] = rBh[1];
        if constexpr (APL == 2) { *(short8*)&Asl[wofs0] = rAl[0]; *(short8*)&Asl[wofs1] = rAl[1]; }
        if constexpr (BPL == 2) { *(short8*)&Bsl[wofs0] = rBl[0]; *(short8*)&Bsl[wofs1] = rBl[1]; }
        __syncthreads();   // tile ready

        if (k0 + 32 < K) LOADREGS(k0 + 32);   // prefetch next tile into regs

        short8 a_h[4], a_l[4], b_h[4], b_l[4];
#pragma unroll
        for (int i = 0; i < 4; ++i) {
            const int ra = wm + i * 16 + l15;
            const int ca = ra * 32 + ((l4 ^ ((ra >> 1) & 3)) << 3);
            a_h[i] = *(const short8*)&Ash[ca];
            if constexpr (APL == 2) a_l[i] = *(const short8*)&Asl[ca];
            const int rb = wn + i * 16 + l15;
            const int cb = rb * 32 + ((l4 ^ ((rb >> 1) & 3)) << 3);
            b_h[i] = *(const short8*)&Bsh[cb];
            if constexpr (BPL == 2) b_l[i] = *(const short8*)&Bsl[cb];
        }
#pragma unroll
        for (int i = 0; i < 4; ++i)
#pragma unroll
            for (int j = 0; j < 4; ++j) {
                acc[i][j] = __builtin_amdgcn_mfma_f32_16x16x32_bf16(a_h[i], b_h[j], acc[i][j], 0, 0, 0);
                if constexpr (NPROD >= 2)
                    acc[i][j] = __builtin_amdgcn_mfma_f32_16x16x32_bf16(a_h[i], b_l[j], acc[i][j], 0, 0, 0);
                if constexpr (NPROD >= 3)
                    acc[i][j] = __builtin_amdgcn_mfma_f32_16x16x32_bf16(a_l[i], b_h[j], acc[i][j], 0, 0, 0);
            }
    }
#undef LOADREGS

    // ---- epilogue ----
#pragma unroll
    for (int j = 0; j < 4; ++j) {
        const int col = n0 + wn + j * 16 + l15;
        float bv = 0.f;
        if constexpr (BIASMODE == 1) bv = bias0[col];
        if constexpr (BIASMODE == 2) bv = (col < 1024) ? bias0[col] : bias1[col - 1024];
#pragma unroll
        for (int i = 0; i < 4; ++i) {
            const int rbase = m0 + wm + i * 16 + l4 * 4;
            float vals[4];
            vals[0] = acc[i][j].x * alpha + bv;
            vals[1] = acc[i][j].y * alpha + bv;
            vals[2] = acc[i][j].z * alpha + bv;
            vals[3] = acc[i][j].w * alpha + bv;
            if constexpr (CMODE == 0) {
#pragma unroll
                for (int r = 0; r < 4; ++r)
                    Cf[(long)z * sCz + (long)(rbase + r) * ldc + col] = vals[r];
            } else if constexpr (CMODE == 1) {
                ushort* Ch = (col < 1024) ? Ch0 : Ch1;
                ushort* Cl = (col < 1024) ? Cl0 : Cl1;
                const int cc = col & 1023;
#pragma unroll
                for (int r = 0; r < 4; ++r) {
                    const long idx = (long)(rbase + r) * 1024 + cc;
                    unsigned u  = __builtin_bit_cast(unsigned, vals[r]);
                    unsigned ur = u + 0x7fffu + ((u >> 16) & 1u);
                    float hif   = __builtin_bit_cast(float, ur & 0xffff0000u);
                    Ch[idx] = (ushort)(ur >> 16);
                    Cl[idx] = (ushort)(__builtin_bit_cast(unsigned, vals[r] - hif) >> 16);
                }
            } else {  // CMODE == 2: vT[row>>11][col][row&2047]
                const int z2 = rbase >> 11;
                const int s0 = rbase & 2047;
                ushort4v p;
                p[0] = bf16_rne(vals[0]); p[1] = bf16_rne(vals[1]);
                p[2] = bf16_rne(vals[2]); p[3] = bf16_rne(vals[3]);
                *(ushort4v*)&Ch0[(long)z2 * DOUT * S_LEN + (long)col * S_LEN + s0] = p;
            }
        }
    }
}

// ---------------------------------------------------------------------------
// x1 f32 -> bf16 (plain RNE), 8 elems/thread
// ---------------------------------------------------------------------------
__global__ __launch_bounds__(256)
void split_x1(const float* __restrict__ x, ushort* __restrict__ xh)
{
    const long i = ((long)blockIdx.x * 256 + threadIdx.x) * 8;
    float f[8];
    *(float4*)&f[0] = *(const float4*)(x + i);
    *(float4*)&f[4] = *(const float4*)(x + i + 4);
    short8 h;
    plain8(f, h);
    *(short8*)&xh[i] = h;
}

// ---------------------------------------------------------------------------
// Wq,Wk [4096,1024] f32 -> concatenated transposed split planes
// Dh/Dl [2048][4096] bf16 (rows 0-1023 = Wq^T, 1024-2047 = Wk^T)
// ---------------------------------------------------------------------------
__global__ __launch_bounds__(256)
void wsplit_qk(const float* __restrict__ W0, const float* __restrict__ W1,
               ushort* __restrict__ Dh, ushort* __restrict__ Dl)
{
    const int z = blockIdx.z;
    const float* W = z ? W1 : W0;
    __shared__ float t[64][65];
    const int k0 = blockIdx.y * 64, n0 = blockIdx.x * 64;
    const int tid = threadIdx.x;
#pragma unroll
    for (int i = 0; i < 4; ++i) {
        const int kk = (tid >> 4) + i * 16;
        const int nn = (tid & 15) * 4;
        float4 f = *(const float4*)(W + (long)(k0 + kk) * DOUT + n0 + nn);
        t[kk][nn + 0] = f.x; t[kk][nn + 1] = f.y;
        t[kk][nn + 2] = f.z; t[kk][nn + 3] = f.w;
    }
    __syncthreads();
    const int n = tid >> 2, kc = (tid & 3) * 16;
    float xs[16];
#pragma unroll
    for (int jj = 0; jj < 16; ++jj) xs[jj] = t[kc + jj][n];
    short8 h0, h1, l0, l1;
    split8(xs, h0, l0); split8(xs + 8, h1, l1);
    const long o = (long)(z * 1024 + n0 + n) * DIN + k0 + kc;
    *(short8*)&Dh[o] = h0; *(short8*)&Dh[o + 8] = h1;
    *(short8*)&Dl[o] = l0; *(short8*)&Dl[o + 8] = l1;
}

// Wv [4096,1024] -> Wv^T [1024][4096] bf16 (plain)
__global__ __launch_bounds__(256)
void wsplit_v(const float* __restrict__ W, ushort* __restrict__ Dh)
{
    __shared__ float t[64][65];
    const int k0 = blockIdx.y * 64, n0 = blockIdx.x * 64;
    const int tid = threadIdx.x;
#pragma unroll
    for (int i = 0; i < 4; ++i) {
        const int kk = (tid >> 4) + i * 16;
        const int nn = (tid & 15) * 4;
        float4 f = *(const float4*)(W + (long)(k0 + kk) * DOUT + n0 + nn);
        t[kk][nn + 0] = f.x; t[kk][nn + 1] = f.y;
        t[kk][nn + 2] = f.z; t[kk][nn + 3] = f.w;
    }
    __syncthreads();
    const int n = tid >> 2, kc = (tid & 3) * 16;
    float xs[16];
#pragma unroll
    for (int jj = 0; jj < 16; ++jj) xs[jj] = t[kc + jj][n];
    short8 h0, h1;
    plain8(xs, h0); plain8(xs + 8, h1);
    const long o = (long)(n0 + n) * DIN + k0 + kc;
    *(short8*)&Dh[o] = h0; *(short8*)&Dh[o + 8] = h1;
}

// ---------------------------------------------------------------------------
// Threefry-2x32 (jax_threefry_partitionable=True), key=(0,42):
// per element i: (o0,o1)=threefry((0,42),(0,i)); keep = MSB(o0^o1)==0
// ---------------------------------------------------------------------------
__device__ __forceinline__ unsigned rotl32(unsigned x, int r) {
    return (x << r) | (x >> (32 - r));
}
__device__ __forceinline__ bool tf_keep(unsigned i) {
    const unsigned k0 = 0u, k1 = 42u, k2 = 0x1BD11BF0u;
    unsigned x0 = 0u;
    unsigned x1 = i + k1;
#define TF_R4(r0, r1, r2, r3) \
    x0 += x1; x1 = rotl32(x1, r0); x1 ^= x0; \
    x0 += x1; x1 = rotl32(x1, r1); x1 ^= x0; \
    x0 += x1; x1 = rotl32(x1, r2); x1 ^= x0; \
    x0 += x1; x1 = rotl32(x1, r3); x1 ^= x0;
    TF_R4(13, 15, 26, 6)  x0 += k1; x1 += k2 + 1u;
    TF_R4(17, 29, 16, 24) x0 += k2; x1 += k0 + 2u;
    TF_R4(13, 15, 26, 6)  x0 += k0; x1 += k1 + 3u;
    TF_R4(17, 29, 16, 24) x0 += k1; x1 += k2 + 4u;
    TF_R4(13, 15, 26, 6)  x0 += k2; x1 += k0 + 5u;
#undef TF_R4
    return ((x0 ^ x1) >> 31) == 0u;
}

// ---------------------------------------------------------------------------
// Row softmax + dropout: scores f32 [8192][2048] -> attn bf16 [8192][2048]
// ---------------------------------------------------------------------------
__global__ __launch_bounds__(256)
void softmax_dropout(const float* __restrict__ sc, ushort* __restrict__ attn)
{
    const int r = blockIdx.x;
    const float* row = sc + (long)r * S_LEN;
    const int tid = threadIdx.x;

    float4 v0 = *(const float4*)(row + tid * 4);
    float4 v1 = *(const float4*)(row + 1024 + tid * 4);

    float m = fmaxf(fmaxf(fmaxf(v0.x, v0.y), fmaxf(v0.z, v0.w)),
                    fmaxf(fmaxf(v1.x, v1.y), fmaxf(v1.z, v1.w)));
#pragma unroll
    for (int off = 32; off > 0; off >>= 1) m = fmaxf(m, __shfl_xor(m, off));

    __shared__ float red[8];
    if ((tid & 63) == 0) red[tid >> 6] = m;
    __syncthreads();
    m = fmaxf(fmaxf(red[0], red[1]), fmaxf(red[2], red[3]));

    v0.x = __expf(v0.x - m); v0.y = __expf(v0.y - m);
    v0.z = __expf(v0.z - m); v0.w = __expf(v0.w - m);
    v1.x = __expf(v1.x - m); v1.y = __expf(v1.y - m);
    v1.z = __expf(v1.z - m); v1.w = __expf(v1.w - m);

    float s = v0.x + v0.y + v0.z + v0.w + v1.x + v1.y + v1.z + v1.w;
#pragma unroll
    for (int off = 32; off > 0; off >>= 1) s += __shfl_xor(s, off);
    if ((tid & 63) == 0) red[4 + (tid >> 6)] = s;
    __syncthreads();
    s = red[4] + red[5] + red[6] + red[7];

    const float inv = 2.0f / s;

    const unsigned base0 = (unsigned)r * 2048u + (unsigned)(tid * 4);
    const unsigned base1 = base0 + 1024u;
    float o[8];
    o[0] = tf_keep(base0 + 0u) ? v0.x * inv : 0.f;
    o[1] = tf_keep(base0 + 1u) ? v0.y * inv : 0.f;
    o[2] = tf_keep(base0 + 2u) ? v0.z * inv : 0.f;
    o[3] = tf_keep(base0 + 3u) ? v0.w * inv : 0.f;
    o[4] = tf_keep(base1 + 0u) ? v1.x * inv : 0.f;
    o[5] = tf_keep(base1 + 1u) ? v1.y * inv : 0.f;
    o[6] = tf_keep(base1 + 2u) ? v1.z * inv : 0.f;
    o[7] = tf_keep(base1 + 3u) ? v1.w * inv : 0.f;

    ushort4v p0, p1;
    p0[0] = bf16_rne(o[0]); p0[1] = bf16_rne(o[1]);
    p0[2] = bf16_rne(o[2]); p0[3] = bf16_rne(o[3]);
    p1[0] = bf16_rne(o[4]); p1[1] = bf16_rne(o[5]);
    p1[2] = bf16_rne(o[6]); p1[3] = bf16_rne(o[7]);
    *(ushort4v*)(attn + (long)r * S_LEN + tid * 4)        = p0;
    *(ushort4v*)(attn + (long)r * S_LEN + 1024 + tid * 4) = p1;
}

// ---------------------------------------------------------------------------
extern "C" void kernel_launch(void* const* d_in, const int* in_sizes, int n_in,
                              void* d_out, int out_size, void* d_ws, size_t ws_size,
                              hipStream_t stream)
{
    const float* x1 = (const float*)d_in[0];
    const float* Wq = (const float*)d_in[1];
    const float* bq = (const float*)d_in[2];
    const float* Wk = (const float*)d_in[3];
    const float* bk = (const float*)d_in[4];
    const float* Wv = (const float*)d_in[5];
    const float* bv = (const float*)d_in[6];
    float* out = (float*)d_out;

    const int  M    = NB * S_LEN;               // 8192
    const long SZX  = (long)M * DIN;            // 33,554,432 (x1 bf16 plane)
    const long SZQK = (long)M * DOUT;           //  8,388,608 (q/k bf16 plane)

    // ws layout in ushort units; extent = 83,886,080 ushorts = 167.77 MB
    //  [0, 33.55M)       x1h bf16        -> scores f32 after projections
    //  [33.55M, 67.1M)   qh, ql, kh, kl  -> attn bf16 (33.55M..50.33M) after QK^T
    //  [67.1M, 83.9M)    Whi, Wlo [2048][4096] (phase 1/2a)
    //                    then Wv_h at 67.1M (+4.19M) and vT at 71.3M (+8.39M)
    ushort* wsb   = (ushort*)d_ws;
    ushort* x1h   = wsb;
    float*  scores = (float*)d_ws;
    ushort* qh = wsb + SZX;
    ushort* ql = qh + SZQK;
    ushort* kh = ql + SZQK;
    ushort* kl = kh + SZQK;
    ushort* attn = qh;
    ushort* Whi  = wsb + 2 * SZX;               // 67,108,864
    ushort* Wlo  = Whi + (long)2048 * DIN;
    ushort* Wvh  = Whi;                          // over dead Whi head
    ushort* vT   = Whi + (long)DOUT * DIN;       // 71,303,168, over dead Whi/Wlo

    dim3 blk(256);

    // 1) x1 -> bf16; Wq,Wk -> transposed split planes
    split_x1<<<dim3((int)(SZX / (256 * 8))), blk, 0, stream>>>(x1, x1h);
    wsplit_qk<<<dim3(DOUT / 64, DIN / 64, 2), blk, 0, stream>>>(Wq, Wk, Whi, Wlo);

    // 2a) fused Q,K projection: [8192,4096]bf16 @ [2048,4096]^T split (2 prod)
    mfma_gemm<1, 2, 2, 1, 2><<<dim3(2048 / 128, M / 128, 1), blk, 0, stream>>>(
        x1h, nullptr, Whi, Wlo, bq, bk, 1.f,
        nullptr, qh, ql, kh, kl,
        M, 2048, DIN, DIN, DIN, DOUT, 0, 0, 0);

    // 2b) V projection (plain), output transposed vT[z][d][s]
    wsplit_v<<<dim3(DOUT / 64, DIN / 64, 1), blk, 0, stream>>>(Wv, Wvh);
    mfma_gemm<1, 1, 1, 2, 1><<<dim3(DOUT / 128, M / 128, 1), blk, 0, stream>>>(
        x1h, nullptr, Wvh, nullptr, bv, nullptr, 1.f,
        nullptr, vT, nullptr, nullptr, nullptr,
        M, DOUT, DIN, DIN, DIN, DOUT, 0, 0, 0);

    // 3) scores = q @ k^T / 32 per batch (3-product split)
    mfma_gemm<2, 2, 3, 0, 0><<<dim3(S_LEN / 128, S_LEN / 128, NB), blk, 0, stream>>>(
        qh, ql, kh, kl, nullptr, nullptr, 1.f / 32.f,
        scores, nullptr, nullptr, nullptr, nullptr,
        S_LEN, S_LEN, DOUT, DOUT, DOUT, S_LEN,
        (long)S_LEN * DOUT, (long)S_LEN * DOUT, (long)S_LEN * S_LEN);

    // 4) softmax + exact-JAX dropout -> attn bf16
    softmax_dropout<<<dim3(M), blk, 0, stream>>>(scores, attn);

    // 5) out = attn @ vT^T per batch (plain bf16)
    mfma_gemm<1, 1, 1, 0, 0><<<dim3(DOUT / 128, S_LEN / 128, NB), blk, 0, stream>>>(
        attn, nullptr, vT, nullptr, nullptr, nullptr, 1.f,
        out, nullptr, nullptr, nullptr, nullptr,
        S_LEN, DOUT, S_LEN, S_LEN, S_LEN, DOUT,
        (long)S_LEN * S_LEN, (long)DOUT * S_LEN, (long)S_LEN * DOUT);
}